// Round 1
// baseline (432.744 us; speedup 1.0000x reference)
//
#include <hip/hip_runtime.h>

// Problem constants (from setup_inputs): N=8, C=16, H=32, W=32, T=500.
#define T_LEN 500
#define CHW   16384          // C*H*W = 16*32*32 (power of 2)
#define VECS  125            // T_LEN / 4

// out[t] = (1-frac)*g(t-si) + frac*g(t-si-1), g zero-padded outside [0,T).
// si = floor(delay/Ts), frac = delay/Ts - si; (si,frac) per (c,h,w) row.
__global__ __launch_bounds__(256) void _delayLayer_2576980377764_kernel(
    const float* __restrict__ x,       // (N,C,H,W,T) flat
    const float* __restrict__ delay,   // (C,H,W) flat
    const int*   __restrict__ Ts_ptr,  // scalar (Python int -> int32)
    float* __restrict__ out,
    int total_vecs)                    // N*C*H*W*T/4
{
    int gid = blockIdx.x * blockDim.x + threadIdx.x;
    if (gid >= total_vecs) return;

    float Ts = (float)(*Ts_ptr);       // broadcast, L1-resident

    int r = gid / VECS;                // row id over (N,C,H,W)
    int v = gid - r * VECS;            // which float4 within the row
    int chw = r & (CHW - 1);

    float s    = delay[chw] / Ts;
    float sif  = floorf(s);
    float frac = s - sif;
    int   si   = (int)sif;

    const float* row = x + (size_t)r * T_LEN;
    int t0   = v * 4;
    int base = t0 - si;                // gather index for output t0

    // Load 5 overlapping inputs -> 4 outputs (g1[t] == g0[t-1] reuse).
    float g[5];
#pragma unroll
    for (int j = 0; j < 5; ++j) {
        int i = base - 1 + j;
        g[j] = (i >= 0 && i < T_LEN) ? row[i] : 0.0f;
    }

    float4 o;
    o.x = (1.0f - frac) * g[1] + frac * g[0];
    o.y = (1.0f - frac) * g[2] + frac * g[1];
    o.z = (1.0f - frac) * g[3] + frac * g[2];
    o.w = (1.0f - frac) * g[4] + frac * g[3];

    // rows are 500 floats = 2000 B (16B-multiple), t0 is a multiple of 4
    // floats -> 16B-aligned vector store.
    *reinterpret_cast<float4*>(out + (size_t)r * T_LEN + t0) = o;
}

extern "C" void kernel_launch(void* const* d_in, const int* in_sizes, int n_in,
                              void* d_out, int out_size, void* d_ws, size_t ws_size,
                              hipStream_t stream) {
    const float* x     = (const float*)d_in[0];
    const float* delay = (const float*)d_in[1];
    const int*   Ts    = (const int*)d_in[2];
    float*       out   = (float*)d_out;

    int total_vecs = in_sizes[0] / 4;          // 16,384,000
    int blocks = (total_vecs + 255) / 256;     // 64,000 blocks of 256

    _delayLayer_2576980377764_kernel<<<blocks, 256, 0, stream>>>(
        x, delay, Ts, out, total_vecs);
}

// Round 3
// 419.830 us; speedup vs baseline: 1.0308x; 1.0308x over previous
//
#include <hip/hip_runtime.h>

// Problem constants (from setup_inputs): N=8, C=16, H=32, W=32, T=500.
#define T_LEN 500
#define CHW   16384          // C*H*W = 16*32*32 (power of 2)
#define VECS  125            // T_LEN / 4

// Native vector type: __builtin_nontemporal_store requires a vector of
// scalars, not HIP's float4 class type.
typedef float v4f __attribute__((ext_vector_type(4)));

// out[t] = (1-frac)*x[t-si] + frac*x[t-si-1], zero-padded outside [0,T).
// si = floor(delay/Ts), frac = delay/Ts - si; (si,frac) per (c,h,w) row.
// setup_inputs: delay ~ U[0,1), Ts=1  =>  si == 0 for every row (fast path);
// general path retained for correctness on any si.
__global__ __launch_bounds__(256) void _delayLayer_2576980377764_kernel(
    const float* __restrict__ x,       // (N,C,H,W,T) flat
    const float* __restrict__ delay,   // (C,H,W) flat
    const int*   __restrict__ Ts_ptr,  // scalar (Python int -> int32)
    float* __restrict__ out,
    int total_vecs)                    // N*C*H*W*T/4
{
    int gid = blockIdx.x * blockDim.x + threadIdx.x;
    if (gid >= total_vecs) return;

    float Ts = (float)(*Ts_ptr);       // broadcast, cache-resident

    int r   = gid / VECS;              // row id over (N,C,H,W)
    int v   = gid - r * VECS;          // which float4 within the row
    int chw = r & (CHW - 1);

    float s    = delay[chw] / Ts;
    float sif  = floorf(s);
    float frac = s - sif;
    int   si   = (int)sif;

    const float* row = x + (size_t)r * T_LEN;
    int t0 = v * 4;

    v4f o;
    float a = 1.0f - frac;

    if (si == 0) {
        // Fast path (wave-uniform in practice): aligned vec4 load + 1 scalar.
        v4f c = *reinterpret_cast<const v4f*>(row + t0);
        float prev = 0.0f;
        if (t0 > 0) prev = row[t0 - 1];   // predicated; t0==0 -> zero-pad
        o.x = a * c.x + frac * prev;
        o.y = a * c.y + frac * c.x;
        o.z = a * c.z + frac * c.y;
        o.w = a * c.w + frac * c.z;
    } else {
        // General path: 5 bounds-checked scalar gathers -> 4 outputs.
        int base = t0 - si;
        float g[5];
#pragma unroll
        for (int j = 0; j < 5; ++j) {
            int i = base - 1 + j;
            g[j] = (i >= 0 && i < T_LEN) ? row[i] : 0.0f;
        }
        o.x = a * g[1] + frac * g[0];
        o.y = a * g[2] + frac * g[1];
        o.z = a * g[3] + frac * g[2];
        o.w = a * g[4] + frac * g[3];
    }

    // Rows are 500 floats = 2000 B (16B-multiple), t0 multiple of 4 floats
    // -> 16B-aligned store. Output is never re-read: nontemporal.
    __builtin_nontemporal_store(
        o, reinterpret_cast<v4f*>(out + (size_t)r * T_LEN + t0));
}

extern "C" void kernel_launch(void* const* d_in, const int* in_sizes, int n_in,
                              void* d_out, int out_size, void* d_ws, size_t ws_size,
                              hipStream_t stream) {
    const float* x     = (const float*)d_in[0];
    const float* delay = (const float*)d_in[1];
    const int*   Ts    = (const int*)d_in[2];
    float*       out   = (float*)d_out;

    int total_vecs = in_sizes[0] / 4;          // 16,384,000
    int blocks = (total_vecs + 255) / 256;     // 64,000 blocks of 256

    _delayLayer_2576980377764_kernel<<<blocks, 256, 0, stream>>>(
        x, delay, Ts, out, total_vecs);
}